// Round 17
// baseline (1711.341 us; speedup 1.0000x reference)
//
#include <hip/hip_runtime.h>

// ---------------------------------------------------------------------------
// Encoder_Decoder v17 = v15 with weight chunks forced into AGPRs ("+a" asm).
// v12-v16: allocator caps long-lived VGPRs at ~48 (VGPR_Count ~96) and
// silently re-streams the remaining weight chunks from L2 every step
// (~196KB/step ~ 2280cy at the ~86B/cy per-CU wall -> the observed 3550cy
// step). The unified gfx950 register file's AGPR half is the one residency
// mechanism not yet tried: "+a" constraints park each weight dword in an
// accumulation register (decoder 144 AGPR + ~96 VGPR = 240 <= 256 budget at
// waves_per_eu(2,2); encoder 96 + ~80 = 176). Worst case the compiler emits
// v_accvgpr_read per use (+~144 VALU cyc/step) -- cheap vs 2280cy streaming.
//   decoder: ic0..35 AGPR, ic36..47 LDS (98KB). encoder: all 24 chunks AGPR.
// ---------------------------------------------------------------------------

typedef __fp16 h2v __attribute__((ext_vector_type(2)));

__device__ __forceinline__ h2v pk2(float a, float b) {
  return __builtin_amdgcn_cvt_pkrtz(a, b);
}
__device__ __forceinline__ unsigned h2u(h2v h) { return __builtin_bit_cast(unsigned, h); }
__device__ __forceinline__ h2v u2h(unsigned u) { return __builtin_bit_cast(h2v, u); }
__device__ __forceinline__ float fdot2f(h2v a, h2v b, float c) {
  return __builtin_amdgcn_fdot2(a, b, c, false);
}
__device__ __forceinline__ float sigf(float x) { return 1.f / (1.f + __expf(-x)); }
__device__ __forceinline__ float tanhfast(float x) { return 2.f / (1.f + __expf(-2.f * x)) - 1.f; }

__device__ __forceinline__ uint4 pack8u(float4 a, float4 b) {
  uint4 o;
  o.x = h2u(pk2(a.x, a.y)); o.y = h2u(pk2(a.z, a.w));
  o.z = h2u(pk2(b.x, b.y)); o.w = h2u(pk2(b.z, b.w));
  return o;
}

__device__ __forceinline__ float dotu4(uint4 cv, h2v a0, h2v a1, h2v a2, h2v a3,
                                       float acc) {
  acc = fdot2f(u2h(cv.x), a0, acc);
  acc = fdot2f(u2h(cv.y), a1, acc);
  acc = fdot2f(u2h(cv.z), a2, acc);
  acc = fdot2f(u2h(cv.w), a3, acc);
  return acc;
}

template <int CTRL>
__device__ __forceinline__ float dppadd(float acc, float v) {
  int r = __builtin_amdgcn_update_dpp(0, __float_as_int(v), CTRL, 0xF, 0xF, true);
  return acc + __int_as_float(r);
}
__device__ __forceinline__ float swz4add(float acc, float v) {
  return acc + __int_as_float(__builtin_amdgcn_ds_swizzle(__float_as_int(v), 0x101F));
}

// 8 partials, slot k on lane holds row-id k^(m&7); returns row-id (m&7) sum.
__device__ __forceinline__ float reduce8s(float p0, float p1, float p2, float p3,
                                          float p4, float p5, float p6, float p7) {
  p0 = dppadd<0xB1>(p0, p1);
  p2 = dppadd<0xB1>(p2, p3);
  p4 = dppadd<0xB1>(p4, p5);
  p6 = dppadd<0xB1>(p6, p7);
  p0 = dppadd<0x4E>(p0, p2);
  p4 = dppadd<0x4E>(p4, p6);
  p0 = swz4add(p0, p4);
  p0 = dppadd<0x128>(p0, p0);
  return p0;
}

// Park a loaded uint4 in AGPRs (accumulation half of the unified file).
#define OPA(v) asm volatile("" : "+a"((v).x), "+a"((v).y), "+a"((v).z), "+a"((v).w))

#define BAR_LGKM()                                     \
  asm volatile("s_waitcnt lgkmcnt(0)" ::: "memory");   \
  __builtin_amdgcn_s_barrier();                        \
  asm volatile("" ::: "memory");

// ---------------------------------------------------------------------------
// K0: fill allf[:,128:224]
// ---------------------------------------------------------------------------
__global__ void k_fill_misc(const float* __restrict__ score, const float* __restrict__ box,
                            const float* __restrict__ orig, float* __restrict__ allf) {
  int i = blockIdx.x * blockDim.x + threadIdx.x;
  if (i >= 40960 * 96) return;
  int row = i / 96, k = i - row * 96;
  float v;
  if (k == 0) v = score[row];
  else if (k < 5) v = box[row * 4 + (k - 1)];
  else v = orig[(size_t)row * 91 + (k - 5)];
  allf[(size_t)row * 224 + 128 + k] = v;
}

// ---------------------------------------------------------------------------
// K1: allf[:,0:128] = relu(feat @ appear_W^T + appear_b)
// ---------------------------------------------------------------------------
__global__ __launch_bounds__(256) void k_gemm_appear(
    const float* __restrict__ A, const float* __restrict__ W,
    const float* __restrict__ bias, float* __restrict__ allf) {
  __shared__ float As[32][68];
  __shared__ float Ws[32][132];
  const int tid = threadIdx.x;
  const int tx = tid & 15, ty = tid >> 4;
  const int r0 = blockIdx.x * 64;
  const int lr = tid >> 3;
  const int lk = (tid & 7) * 4;
  float acc[4][8];
#pragma unroll
  for (int i = 0; i < 4; ++i)
#pragma unroll
    for (int j = 0; j < 8; ++j) acc[i][j] = 0.f;

  for (int k0 = 0; k0 < 1024; k0 += 32) {
#pragma unroll
    for (int i = 0; i < 2; ++i) {
      int rr = lr + i * 32;
      float4 v = *(const float4*)(A + (size_t)(r0 + rr) * 1024 + k0 + lk);
      As[lk + 0][rr] = v.x; As[lk + 1][rr] = v.y; As[lk + 2][rr] = v.z; As[lk + 3][rr] = v.w;
    }
#pragma unroll
    for (int i = 0; i < 4; ++i) {
      int wr = lr + i * 32;
      float4 v = *(const float4*)(W + (size_t)wr * 1024 + k0 + lk);
      Ws[lk + 0][wr] = v.x; Ws[lk + 1][wr] = v.y; Ws[lk + 2][wr] = v.z; Ws[lk + 3][wr] = v.w;
    }
    __syncthreads();
#pragma unroll
    for (int kk = 0; kk < 32; ++kk) {
      float4 a = *(const float4*)&As[kk][ty * 4];
      float4 w0 = *(const float4*)&Ws[kk][tx * 8];
      float4 w1 = *(const float4*)&Ws[kk][tx * 8 + 4];
      float av[4] = {a.x, a.y, a.z, a.w};
      float wv[8] = {w0.x, w0.y, w0.z, w0.w, w1.x, w1.y, w1.z, w1.w};
#pragma unroll
      for (int i = 0; i < 4; ++i)
#pragma unroll
        for (int j = 0; j < 8; ++j) acc[i][j] = fmaf(av[i], wv[j], acc[i][j]);
    }
    __syncthreads();
  }
#pragma unroll
  for (int i = 0; i < 4; ++i) {
    int row = r0 + ty * 4 + i;
#pragma unroll
    for (int j = 0; j < 8; ++j) {
      int col = tx * 8 + j;
      float v = acc[i][j] + bias[col];
      allf[(size_t)row * 224 + col] = fmaxf(v, 0.f);
    }
  }
}

// ---------------------------------------------------------------------------
// K2: enc_feat = relu(allf @ featlin_W^T + b), stored packed f16x2
// ---------------------------------------------------------------------------
__global__ __launch_bounds__(256) void k_gemm_featlin(
    const float* __restrict__ A, const float* __restrict__ W,
    const float* __restrict__ bias, unsigned* __restrict__ encf2) {
  __shared__ float As[32][68];
  __shared__ float Ws[32][132];
  const int tid = threadIdx.x;
  const int tx = tid & 15, ty = tid >> 4;
  const int r0 = blockIdx.x * 64;
  const int lr = tid >> 3;
  const int lk = (tid & 7) * 4;
  float acc[4][8];
#pragma unroll
  for (int i = 0; i < 4; ++i)
#pragma unroll
    for (int j = 0; j < 8; ++j) acc[i][j] = 0.f;

  for (int k0 = 0; k0 < 224; k0 += 32) {
#pragma unroll
    for (int i = 0; i < 2; ++i) {
      int rr = lr + i * 32;
      float4 v = *(const float4*)(A + (size_t)(r0 + rr) * 224 + k0 + lk);
      As[lk + 0][rr] = v.x; As[lk + 1][rr] = v.y; As[lk + 2][rr] = v.z; As[lk + 3][rr] = v.w;
    }
#pragma unroll
    for (int i = 0; i < 4; ++i) {
      int wr = lr + i * 32;
      float4 v = *(const float4*)(W + (size_t)wr * 224 + k0 + lk);
      Ws[lk + 0][wr] = v.x; Ws[lk + 1][wr] = v.y; Ws[lk + 2][wr] = v.z; Ws[lk + 3][wr] = v.w;
    }
    __syncthreads();
#pragma unroll
    for (int kk = 0; kk < 32; ++kk) {
      float4 a = *(const float4*)&As[kk][ty * 4];
      float4 w0 = *(const float4*)&Ws[kk][tx * 8];
      float4 w1 = *(const float4*)&Ws[kk][tx * 8 + 4];
      float av[4] = {a.x, a.y, a.z, a.w};
      float wv[8] = {w0.x, w0.y, w0.z, w0.w, w1.x, w1.y, w1.z, w1.w};
#pragma unroll
      for (int i = 0; i < 4; ++i)
#pragma unroll
        for (int j = 0; j < 8; ++j) acc[i][j] = fmaf(av[i], wv[j], acc[i][j]);
    }
    __syncthreads();
  }
#pragma unroll
  for (int i = 0; i < 4; ++i) {
    int row = r0 + ty * 4 + i;
    unsigned* orow = encf2 + (size_t)row * 64;
#pragma unroll
    for (int p = 0; p < 4; ++p) {
      int col = tx * 8 + 2 * p;
      float a = fmaxf(acc[i][2 * p] + bias[col], 0.f);
      float b = fmaxf(acc[i][2 * p + 1] + bias[col + 1], 0.f);
      orow[tx * 4 + p] = h2u(pk2(a, b));
    }
  }
}

// ---------------------------------------------------------------------------
// K3: decoder input projections gi[c][v][r] (bih folded in)
// ---------------------------------------------------------------------------
__global__ __launch_bounds__(256) void k_dec_gi(
    const float* __restrict__ Wih, const float* __restrict__ bih,
    const float* __restrict__ emb, float* __restrict__ gi) {
  __shared__ float e[4][32];
  const int c = blockIdx.x, tid = threadIdx.x;
  if (tid < 128) e[tid >> 5][tid & 31] = emb[tid];
  __syncthreads();
#pragma unroll
  for (int i = 0; i < 3; ++i) {
    int r = tid + i * 256;
    const float* w = Wih + ((size_t)c * 768 + r) * 32;
    float b = bih[(size_t)c * 768 + r];
    float a0 = b, a1 = b, a2 = b, a3 = b;
#pragma unroll
    for (int k = 0; k < 32; ++k) {
      float wv = w[k];
      a0 = fmaf(wv, e[0][k], a0);
      a1 = fmaf(wv, e[1][k], a1);
      a2 = fmaf(wv, e[2][k], a2);
      a3 = fmaf(wv, e[3][k], a3);
    }
    gi[((size_t)c * 4 + 0) * 768 + r] = a0;
    gi[((size_t)c * 4 + 1) * 768 + r] = a1;
    gi[((size_t)c * 4 + 2) * 768 + r] = a2;
    gi[((size_t)c * 4 + 3) * 768 + r] = a3;
  }
}

// ---------------------------------------------------------------------------
// K3b: pack dec_Whh -> f16 chunks (v12 layout). ic = gt*16 + k*2 + hf.
// Thread (G,m,mw): row = gt*256 + 8G + (k^mw), cols 16m+8hf..+7.
// ---------------------------------------------------------------------------
__global__ __launch_bounds__(512) void k_pack_dec(
    const float* __restrict__ Whh, uint4* __restrict__ wpk) {
  const int c = blockIdx.x / 48, ic = blockIdx.x % 48;
  const int tid = threadIdx.x;
  const int G = tid >> 4, m = tid & 15, mw = m & 7;
  const int gt = ic >> 4, k = (ic & 15) >> 1, hf = ic & 1;
  const int row = gt * 256 + 8 * G + (k ^ mw);
  const float* src = Whh + ((size_t)c * 768 + row) * 256 + 16 * m + 8 * hf;
  wpk[((size_t)c * 48 + ic) * 512 + tid] =
      pack8u(*(const float4*)src, *(const float4*)(src + 4));
}

// ---------------------------------------------------------------------------
// K4: encoder GRU, all 24 weight chunks parked in AGPRs.
// 160 blocks x 512 threads, waves_per_eu(2,2).
// ---------------------------------------------------------------------------
#define ELOAD(gt, k, DST)                                                          \
  {                                                                                \
    int rid_ = (k) ^ mw;                                                           \
    const float* Mx_ = ((k) & 1) ? baseB : baseA;                                  \
    const float4* ps_ =                                                            \
        (const float4*)(Mx_ + ((size_t)((gt) * 128 + 4 * G + (rid_ >> 1))) * 128 + \
                        8 * m);                                                    \
    DST = pack8u(ps_[0], ps_[1]);                                                  \
    OPA(DST);                                                                      \
  }                                                                                \
  __builtin_amdgcn_sched_barrier(0);

__global__ __launch_bounds__(512)
__attribute__((amdgpu_waves_per_eu(2, 2))) void k_enc_gru(
    const unsigned* __restrict__ encf2,
    const float* __restrict__ WihF, const float* __restrict__ WhhF,
    const float* __restrict__ bihF, const float* __restrict__ bhhF,
    const float* __restrict__ WihB, const float* __restrict__ WhhB,
    const float* __restrict__ bihB, const float* __restrict__ bhhB,
    float* __restrict__ dec_h0) {
  const int blk = blockIdx.x;
  const int c = blk >> 1, dir = blk & 1;
  const int tid = threadIdx.x;
  const int G = tid >> 4, m = tid & 15, mw = m & 7;

  const float* Wih = (dir ? WihB : WihF) + (size_t)c * 384 * 128;
  const float* Whh = (dir ? WhhB : WhhF) + (size_t)c * 384 * 128;
  const float* bih = (dir ? bihB : bihF) + (size_t)c * 384;
  const float* bhh = (dir ? bhhB : bhhF) + (size_t)c * 384;

  const float* baseA = (mw & 1) ? Whh : Wih;  // for even k
  const float* baseB = (mw & 1) ? Wih : Whh;  // for odd  k

  __shared__ __align__(16) unsigned x2s[2][64];
  __shared__ __align__(16) unsigned h2s[2][64];

  uint4 er0, er1, er2, er3, er4, er5, er6, er7;
  uint4 ez0, ez1, ez2, ez3, ez4, ez5, ez6, ez7;
  uint4 en0, en1, en2, en3, en4, en5, en6, en7;
  ELOAD(0, 0, er0) ELOAD(0, 1, er1) ELOAD(0, 2, er2) ELOAD(0, 3, er3)
  ELOAD(0, 4, er4) ELOAD(0, 5, er5) ELOAD(0, 6, er6) ELOAD(0, 7, er7)
  ELOAD(1, 0, ez0) ELOAD(1, 1, ez1) ELOAD(1, 2, ez2) ELOAD(1, 3, ez3)
  ELOAD(1, 4, ez4) ELOAD(1, 5, ez5) ELOAD(1, 6, ez6) ELOAD(1, 7, ez7)
  ELOAD(2, 0, en0) ELOAD(2, 1, en1) ELOAD(2, 2, en2) ELOAD(2, 3, en3)
  ELOAD(2, 4, en4) ELOAD(2, 5, en5) ELOAD(2, 6, en6) ELOAD(2, 7, en7)

  const int u = 4 * G + (mw >> 1);
  const float brz_r = bih[u] + bhh[u];
  const float brz_z = bih[128 + u] + bhh[128 + u];
  const float b_in = bih[256 + u];
  const float b_hn = bhh[256 + u];

  if (tid < 64) h2s[0][tid] = 0u;
  if (tid >= 448) {
    int lane = tid - 448;
    x2s[0][lane] = (dir == 0) ? encf2[((size_t)c * 512 + 0) * 64 + lane] : 0x3C003C00u;
  }
  float hreg = 0.f;
  __syncthreads();

  for (int t = 0; t <= 512; ++t) {
    unsigned xpre = 0;
    if (tid >= 448 && t < 512) {
      int tn = t + 1, lane = tid - 448;
      int row = (dir == 0) ? ((tn < 512) ? tn : -1) : (512 - tn);
      xpre = (row < 0) ? 0x3C003C00u : encf2[((size_t)c * 512 + row) * 64 + lane];
    }
    uint4 xv = ((const uint4*)&x2s[t & 1][0])[m];
    uint4 hv = ((const uint4*)&h2s[t & 1][0])[m];
    h2v x0 = u2h(xv.x), x1 = u2h(xv.y), x2 = u2h(xv.z), x3 = u2h(xv.w);
    h2v hh0 = u2h(hv.x), hh1 = u2h(hv.y), hh2 = u2h(hv.z), hh3 = u2h(hv.w);
    bool oddl = (mw & 1);
    h2v a0 = oddl ? hh0 : x0, a1 = oddl ? hh1 : x1, a2 = oddl ? hh2 : x2, a3 = oddl ? hh3 : x3;
    h2v b0 = oddl ? x0 : hh0, b1 = oddl ? x1 : hh1, b2 = oddl ? x2 : hh2, b3 = oddl ? x3 : hh3;
#define EA(ch) dotu4(ch, a0, a1, a2, a3, 0.f)
#define EB(ch) dotu4(ch, b0, b1, b2, b3, 0.f)
    float vR = reduce8s(EA(er0), EB(er1), EA(er2), EB(er3),
                        EA(er4), EB(er5), EA(er6), EB(er7));
    float vZ = reduce8s(EA(ez0), EB(ez1), EA(ez2), EB(ez3),
                        EA(ez4), EB(ez5), EA(ez6), EB(ez7));
    float vN = reduce8s(EA(en0), EB(en1), EA(en2), EB(en3),
                        EA(en4), EB(en5), EA(en6), EB(en7));
#undef EA
#undef EB
    float oR = __shfl_xor(vR, 1, 64);
    float oZ = __shfl_xor(vZ, 1, 64);
    float oN = __shfl_xor(vN, 1, 64);
    float r = sigf(vR + oR + brz_r);
    float z = sigf(vZ + oZ + brz_z);
    float i_n = oddl ? oN : vN;
    float h_n = oddl ? vN : oN;
    float n = tanhfast(i_n + b_in + r * (h_n + b_hn));
    float hn = (1.f - z) * n + z * hreg;
    hreg = hn;
    float prt = __shfl_xor(hn, 2, 64);
    if (m < 8 && (mw & 3) == 0) h2s[(t + 1) & 1][2 * G + (mw >> 2)] = h2u(pk2(hn, prt));
    if (tid >= 448 && t < 512) x2s[(t + 1) & 1][tid - 448] = xpre;
    BAR_LGKM();
  }
  if ((m < 8) && ((mw & 1) == 0))
    dec_h0[(size_t)c * 256 + dir * 128 + u] = hreg;
}

// ---------------------------------------------------------------------------
// K5: decoder GRU, fused gates, 1 barrier/step, deferred out-proj.
// 80 blocks x 512 threads, waves_per_eu(2,2).
// Split: ic0..35 in AGPRs (144), ic36..47 LDS (98KB), 0 streamed.
// ---------------------------------------------------------------------------
#define CONSX(sa, sb) dotu4(sb, g4, g5, g6, g7, dotu4(sa, g0, g1, g2, g3, 0.f))
#define LD4A(a, b, cc, d, base)                                                \
  uint4 a = wp[(base + 0) * 512], b = wp[(base + 1) * 512],                    \
        cc = wp[(base + 2) * 512], d = wp[(base + 3) * 512];                   \
  OPA(a); OPA(b); OPA(cc); OPA(d);                                             \
  __builtin_amdgcn_sched_barrier(0);

__global__ __launch_bounds__(512)
__attribute__((amdgpu_waves_per_eu(2, 2))) void k_dec_gru(
    const uint4* __restrict__ wpk, const float* __restrict__ bhh,
    const float* __restrict__ gi, const float* __restrict__ h0,
    const int* __restrict__ labels, unsigned* __restrict__ dhs2) {
  const int c = blockIdx.x, tid = threadIdx.x;
  const int G = tid >> 4, m = tid & 15, mw = m & 7;

  __shared__ __align__(16) unsigned h2s[2][128];
  __shared__ int labs[513];
  __shared__ __align__(16) uint4 wlds[12 * 512];  // 98304 B

  const uint4* wp = wpk + (size_t)c * 48 * 512 + tid;

  // LDS-resident chunks ic36..47
  for (int j = 0; j < 12; ++j) wlds[j * 512 + tid] = wp[(36 + j) * 512];
  __builtin_amdgcn_sched_barrier(0);
  // AGPR chunks ic0..35
  LD4A(ra0, ra1, ra2, ra3, 0)
  LD4A(ra4, ra5, ra6, ra7, 4)
  LD4A(ra8, ra9, ra10, ra11, 8)
  LD4A(ra12, ra13, ra14, ra15, 12)
  LD4A(ra16, ra17, ra18, ra19, 16)
  LD4A(ra20, ra21, ra22, ra23, 20)
  LD4A(ra24, ra25, ra26, ra27, 24)
  LD4A(ra28, ra29, ra30, ra31, 28)
  LD4A(ra32, ra33, ra34, ra35, 32)

  const int u = 8 * G + mw;
  const float bb0 = bhh[(size_t)c * 768 + u];
  const float bb1 = bhh[(size_t)c * 768 + 256 + u];
  const float bb2 = bhh[(size_t)c * 768 + 512 + u];
  const float* gib = gi + (size_t)c * 4 * 768;
  unsigned* dout = dhs2 + (size_t)c * 513 * 128 + 4 * G + (mw >> 1);

  if (tid < 512) labs[tid + 1] = labels[(size_t)c * 512 + tid];
  if (tid == 0) labs[0] = 2;  // SOS
  float hreg = h0[(size_t)c * 256 + u];
  {
    float oth = __shfl_xor(hreg, 1, 64);
    if (m < 8 && (mw & 1) == 0) h2s[0][4 * G + (mw >> 1)] = h2u(pk2(hreg, oth));
  }
  __syncthreads();

  const uint4* wl = wlds + tid;

  for (int t = 0; t <= 512; ++t) {
    uint4 ha = ((const uint4*)&h2s[t & 1][0])[2 * m];
    uint4 hb = ((const uint4*)&h2s[t & 1][0])[2 * m + 1];
    h2v g0 = u2h(ha.x), g1 = u2h(ha.y), g2 = u2h(ha.z), g3 = u2h(ha.w);
    h2v g4 = u2h(hb.x), g5 = u2h(hb.y), g6 = u2h(hb.z), g7 = u2h(hb.w);
    int sel = labs[t];
    const float* gp = gib + sel * 768;
    float giR = gp[u], giZ = gp[256 + u], giN = gp[512 + u];
    // --- r batch: ic0..15 (AGPR)
    float p0 = CONSX(ra0, ra1), p1 = CONSX(ra2, ra3);
    float p2 = CONSX(ra4, ra5), p3 = CONSX(ra6, ra7);
    float p4 = CONSX(ra8, ra9), p5 = CONSX(ra10, ra11);
    float p6 = CONSX(ra12, ra13), p7 = CONSX(ra14, ra15);
    float rsum = reduce8s(p0, p1, p2, p3, p4, p5, p6, p7);
    // --- z batch: ic16..31 (AGPR)
    p0 = CONSX(ra16, ra17); p1 = CONSX(ra18, ra19);
    p2 = CONSX(ra20, ra21); p3 = CONSX(ra22, ra23);
    p4 = CONSX(ra24, ra25); p5 = CONSX(ra26, ra27);
    p6 = CONSX(ra28, ra29); p7 = CONSX(ra30, ra31);
    float zsum = reduce8s(p0, p1, p2, p3, p4, p5, p6, p7);
    // --- n batch: ic32..35 AGPR + ic36..47 LDS
    p0 = CONSX(ra32, ra33);
    p1 = CONSX(ra34, ra35);
    p2 = CONSX(wl[0 * 512], wl[1 * 512]);
    p3 = CONSX(wl[2 * 512], wl[3 * 512]);
    p4 = CONSX(wl[4 * 512], wl[5 * 512]);
    p5 = CONSX(wl[6 * 512], wl[7 * 512]);
    p6 = CONSX(wl[8 * 512], wl[9 * 512]);
    p7 = CONSX(wl[10 * 512], wl[11 * 512]);
    float nsum = reduce8s(p0, p1, p2, p3, p4, p5, p6, p7);
    // --- fused gates (all on this lane)
    float r = sigf(giR + rsum + bb0);
    float z = sigf(giZ + zsum + bb1);
    float n = tanhfast(giN + r * (nsum + bb2));
    float hn = (1.f - z) * n + z * hreg;
    hreg = hn;
    float oth = __shfl_xor(hn, 1, 64);
    if (m < 8 && (mw & 1) == 0) {
      unsigned pk = h2u(pk2(hn, oth));
      h2s[(t + 1) & 1][4 * G + (mw >> 1)] = pk;
      dout[(size_t)t * 128] = pk;
    }
    BAR_LGKM();
  }
}

// ---------------------------------------------------------------------------
// K5b: out-projection + log_softmax over 41040 rows (1 wave/row).
// ---------------------------------------------------------------------------
__global__ __launch_bounds__(256) void k_out(
    const unsigned* __restrict__ dhs2, const float* __restrict__ outW,
    const float* __restrict__ outB, float* __restrict__ out) {
  int row = blockIdx.x * 4 + (threadIdx.x >> 6);
  if (row >= 41040) return;
  int lane = threadIdx.x & 63;
  const unsigned* hp = dhs2 + (size_t)row * 128 + 2 * lane;
  h2v ha = u2h(hp[0]), hb = u2h(hp[1]);
  float h0f = (float)ha[0], h1f = (float)ha[1], h2f = (float)hb[0], h3f = (float)hb[1];
  float p0, p1, p2, p3;
  {
    const float* w0 = outW + 4 * lane;
    const float* w1 = outW + 256 + 4 * lane;
    const float* w2 = outW + 512 + 4 * lane;
    const float* w3 = outW + 768 + 4 * lane;
    p0 = h0f * w0[0] + h1f * w0[1] + h2f * w0[2] + h3f * w0[3];
    p1 = h0f * w1[0] + h1f * w1[1] + h2f * w1[2] + h3f * w1[3];
    p2 = h0f * w2[0] + h1f * w2[1] + h2f * w2[2] + h3f * w2[3];
    p3 = h0f * w3[0] + h1f * w3[1] + h2f * w3[2] + h3f * w3[3];
  }
#pragma unroll
  for (int off = 32; off > 0; off >>= 1) {
    p0 += __shfl_xor(p0, off, 64);
    p1 += __shfl_xor(p1, off, 64);
    p2 += __shfl_xor(p2, off, 64);
    p3 += __shfl_xor(p3, off, 64);
  }
  if (lane == 0) {
    float l0 = p0 + outB[0], l1 = p1 + outB[1], l2 = p2 + outB[2], l3 = p3 + outB[3];
    float mm = fmaxf(fmaxf(l0, l1), fmaxf(l2, l3));
    float s = __expf(l0 - mm) + __expf(l1 - mm) + __expf(l2 - mm) + __expf(l3 - mm);
    float lse = mm + __logf(s);
    float* o = out + (size_t)row * 4;
    o[0] = l0 - lse; o[1] = l1 - lse; o[2] = l2 - lse; o[3] = l3 - lse;
  }
}

// ---------------------------------------------------------------------------
// K6: labels (as float) and weights passthrough
// ---------------------------------------------------------------------------
__global__ void k_passthrough(const int* __restrict__ labels,
                              const float* __restrict__ weights,
                              float* __restrict__ out) {
  int i = blockIdx.x * blockDim.x + threadIdx.x;
  if (i < 40960) {
    out[164160 + i] = (float)labels[i];
    out[164160 + 40960 + i] = weights[i];
  }
}

// ---------------------------------------------------------------------------
extern "C" void kernel_launch(void* const* d_in, const int* in_sizes, int n_in,
                              void* d_out, int out_size, void* d_ws, size_t ws_size,
                              hipStream_t stream) {
  (void)in_sizes; (void)n_in; (void)out_size; (void)ws_size;
  const float* feat = (const float*)d_in[0];
  const float* score = (const float*)d_in[1];
  const float* box = (const float*)d_in[2];
  const float* orig = (const float*)d_in[3];
  const int* labels = (const int*)d_in[4];
  const float* weights = (const float*)d_in[5];
  const float* appear_W = (const float*)d_in[8];
  const float* appear_b = (const float*)d_in[9];
  const float* featlin_W = (const float*)d_in[10];
  const float* featlin_b = (const float*)d_in[11];
  const float* eWihF = (const float*)d_in[12];
  const float* eWhhF = (const float*)d_in[13];
  const float* ebihF = (const float*)d_in[14];
  const float* ebhhF = (const float*)d_in[15];
  const float* eWihB = (const float*)d_in[16];
  const float* eWhhB = (const float*)d_in[17];
  const float* ebihB = (const float*)d_in[18];
  const float* ebhhB = (const float*)d_in[19];
  const float* dec_emb = (const float*)d_in[20];
  const float* dWih = (const float*)d_in[21];
  const float* dWhh = (const float*)d_in[22];
  const float* dbih = (const float*)d_in[23];
  const float* dbhh = (const float*)d_in[24];
  const float* outW = (const float*)d_in[25];
  const float* outB = (const float*)d_in[26];
  float* out = (float*)d_out;

  char* ws = (char*)d_ws;
  float* allf = (float*)ws;                                     // 36.7MB; reused as wpack
  unsigned* encf2 = (unsigned*)(ws + (size_t)40960 * 224 * 4);  // 10.5MB
  float* dec_h0 = (float*)(ws + (size_t)40960 * 224 * 4 + (size_t)40960 * 64 * 4);
  float* dec_gi = dec_h0 + 80 * 256;                            // 80*4*768 f32
  unsigned* dhs2 = (unsigned*)(dec_gi + 80 * 4 * 768);          // 80*513*128 u32 = 21MB
  uint4* wpack = (uint4*)allf;                                  // 80*48*512*16B = 31.5MB

  k_fill_misc<<<15360, 256, 0, stream>>>(score, box, orig, allf);
  k_gemm_appear<<<640, 256, 0, stream>>>(feat, appear_W, appear_b, allf);
  k_gemm_featlin<<<640, 256, 0, stream>>>(allf, featlin_W, featlin_b, encf2);
  k_pack_dec<<<80 * 48, 512, 0, stream>>>(dWhh, wpack);
  k_dec_gi<<<80, 256, 0, stream>>>(dWih, dbih, dec_emb, dec_gi);
  k_enc_gru<<<160, 512, 0, stream>>>(encf2, eWihF, eWhhF, ebihF, ebhhF,
                                     eWihB, eWhhB, ebihB, ebhhB, dec_h0);
  k_dec_gru<<<80, 512, 0, stream>>>(wpack, dbhh, dec_gi, dec_h0, labels, dhs2);
  k_out<<<10260, 256, 0, stream>>>(dhs2, outW, outB, out);
  k_passthrough<<<160, 256, 0, stream>>>(labels, weights, out);
}

// Round 18
// 1709.223 us; speedup vs baseline: 1.0012x; 1.0012x over previous
//
#include <hip/hip_runtime.h>

// ---------------------------------------------------------------------------
// Encoder_Decoder v18: decoder reverted to v14 (best measured, 707us; proven
// latency-bound, at its structural floor for 1-block/CU occupancy). Encoder
// rebuilt at 1024 threads for 4 waves/SIMD latency hiding: 64 groups x
// 2 units x 3 gates; 8 XOR slots = 2 units x 2 sources x 2 col-halves;
// parity-preselected operands; ALL weights in registers (48 VGPR/thread,
// fits the 128-reg budget at waves_per_eu(4,4)); zero weight LDS/VMEM in
// the loop. Encoder was ~580us at 2 waves/SIMD latency-bound (~2400cy/step
// vs ~640 issue floor) -- doubling wave overlap attacks exactly that gap.
// ---------------------------------------------------------------------------

typedef __fp16 h2v __attribute__((ext_vector_type(2)));

__device__ __forceinline__ h2v pk2(float a, float b) {
  return __builtin_amdgcn_cvt_pkrtz(a, b);
}
__device__ __forceinline__ unsigned h2u(h2v h) { return __builtin_bit_cast(unsigned, h); }
__device__ __forceinline__ h2v u2h(unsigned u) { return __builtin_bit_cast(h2v, u); }
__device__ __forceinline__ float fdot2f(h2v a, h2v b, float c) {
  return __builtin_amdgcn_fdot2(a, b, c, false);
}
__device__ __forceinline__ float sigf(float x) { return 1.f / (1.f + __expf(-x)); }
__device__ __forceinline__ float tanhfast(float x) { return 2.f / (1.f + __expf(-2.f * x)) - 1.f; }

__device__ __forceinline__ uint4 pack8u(float4 a, float4 b) {
  uint4 o;
  o.x = h2u(pk2(a.x, a.y)); o.y = h2u(pk2(a.z, a.w));
  o.z = h2u(pk2(b.x, b.y)); o.w = h2u(pk2(b.z, b.w));
  return o;
}

__device__ __forceinline__ float dotu4(uint4 cv, h2v a0, h2v a1, h2v a2, h2v a3,
                                       float acc) {
  acc = fdot2f(u2h(cv.x), a0, acc);
  acc = fdot2f(u2h(cv.y), a1, acc);
  acc = fdot2f(u2h(cv.z), a2, acc);
  acc = fdot2f(u2h(cv.w), a3, acc);
  return acc;
}

// dot of 4 packed f16 weights (uint2) with 4 packed f16 activations (uint2)
__device__ __forceinline__ float d2(uint2 w, uint2 a) {
  return fdot2f(u2h(w.x), u2h(a.x), fdot2f(u2h(w.y), u2h(a.y), 0.f));
}

template <int CTRL>
__device__ __forceinline__ float dppadd(float acc, float v) {
  int r = __builtin_amdgcn_update_dpp(0, __float_as_int(v), CTRL, 0xF, 0xF, true);
  return acc + __int_as_float(r);
}
__device__ __forceinline__ float swz4add(float acc, float v) {
  return acc + __int_as_float(__builtin_amdgcn_ds_swizzle(__float_as_int(v), 0x101F));
}

// 8 partials, slot k on lane holds row-id k^(m&7); returns row-id (m&7) sum.
__device__ __forceinline__ float reduce8s(float p0, float p1, float p2, float p3,
                                          float p4, float p5, float p6, float p7) {
  p0 = dppadd<0xB1>(p0, p1);
  p2 = dppadd<0xB1>(p2, p3);
  p4 = dppadd<0xB1>(p4, p5);
  p6 = dppadd<0xB1>(p6, p7);
  p0 = dppadd<0x4E>(p0, p2);
  p4 = dppadd<0x4E>(p4, p6);
  p0 = swz4add(p0, p4);
  p0 = dppadd<0x128>(p0, p0);
  return p0;
}

#define BAR_LGKM()                                     \
  asm volatile("s_waitcnt lgkmcnt(0)" ::: "memory");   \
  __builtin_amdgcn_s_barrier();                        \
  asm volatile("" ::: "memory");

// ---------------------------------------------------------------------------
// K0: fill allf[:,128:224]
// ---------------------------------------------------------------------------
__global__ void k_fill_misc(const float* __restrict__ score, const float* __restrict__ box,
                            const float* __restrict__ orig, float* __restrict__ allf) {
  int i = blockIdx.x * blockDim.x + threadIdx.x;
  if (i >= 40960 * 96) return;
  int row = i / 96, k = i - row * 96;
  float v;
  if (k == 0) v = score[row];
  else if (k < 5) v = box[row * 4 + (k - 1)];
  else v = orig[(size_t)row * 91 + (k - 5)];
  allf[(size_t)row * 224 + 128 + k] = v;
}

// ---------------------------------------------------------------------------
// K1: allf[:,0:128] = relu(feat @ appear_W^T + appear_b)
// ---------------------------------------------------------------------------
__global__ __launch_bounds__(256) void k_gemm_appear(
    const float* __restrict__ A, const float* __restrict__ W,
    const float* __restrict__ bias, float* __restrict__ allf) {
  __shared__ float As[32][68];
  __shared__ float Ws[32][132];
  const int tid = threadIdx.x;
  const int tx = tid & 15, ty = tid >> 4;
  const int r0 = blockIdx.x * 64;
  const int lr = tid >> 3;
  const int lk = (tid & 7) * 4;
  float acc[4][8];
#pragma unroll
  for (int i = 0; i < 4; ++i)
#pragma unroll
    for (int j = 0; j < 8; ++j) acc[i][j] = 0.f;

  for (int k0 = 0; k0 < 1024; k0 += 32) {
#pragma unroll
    for (int i = 0; i < 2; ++i) {
      int rr = lr + i * 32;
      float4 v = *(const float4*)(A + (size_t)(r0 + rr) * 1024 + k0 + lk);
      As[lk + 0][rr] = v.x; As[lk + 1][rr] = v.y; As[lk + 2][rr] = v.z; As[lk + 3][rr] = v.w;
    }
#pragma unroll
    for (int i = 0; i < 4; ++i) {
      int wr = lr + i * 32;
      float4 v = *(const float4*)(W + (size_t)wr * 1024 + k0 + lk);
      Ws[lk + 0][wr] = v.x; Ws[lk + 1][wr] = v.y; Ws[lk + 2][wr] = v.z; Ws[lk + 3][wr] = v.w;
    }
    __syncthreads();
#pragma unroll
    for (int kk = 0; kk < 32; ++kk) {
      float4 a = *(const float4*)&As[kk][ty * 4];
      float4 w0 = *(const float4*)&Ws[kk][tx * 8];
      float4 w1 = *(const float4*)&Ws[kk][tx * 8 + 4];
      float av[4] = {a.x, a.y, a.z, a.w};
      float wv[8] = {w0.x, w0.y, w0.z, w0.w, w1.x, w1.y, w1.z, w1.w};
#pragma unroll
      for (int i = 0; i < 4; ++i)
#pragma unroll
        for (int j = 0; j < 8; ++j) acc[i][j] = fmaf(av[i], wv[j], acc[i][j]);
    }
    __syncthreads();
  }
#pragma unroll
  for (int i = 0; i < 4; ++i) {
    int row = r0 + ty * 4 + i;
#pragma unroll
    for (int j = 0; j < 8; ++j) {
      int col = tx * 8 + j;
      float v = acc[i][j] + bias[col];
      allf[(size_t)row * 224 + col] = fmaxf(v, 0.f);
    }
  }
}

// ---------------------------------------------------------------------------
// K2: enc_feat = relu(allf @ featlin_W^T + b), stored packed f16x2
// ---------------------------------------------------------------------------
__global__ __launch_bounds__(256) void k_gemm_featlin(
    const float* __restrict__ A, const float* __restrict__ W,
    const float* __restrict__ bias, unsigned* __restrict__ encf2) {
  __shared__ float As[32][68];
  __shared__ float Ws[32][132];
  const int tid = threadIdx.x;
  const int tx = tid & 15, ty = tid >> 4;
  const int r0 = blockIdx.x * 64;
  const int lr = tid >> 3;
  const int lk = (tid & 7) * 4;
  float acc[4][8];
#pragma unroll
  for (int i = 0; i < 4; ++i)
#pragma unroll
    for (int j = 0; j < 8; ++j) acc[i][j] = 0.f;

  for (int k0 = 0; k0 < 224; k0 += 32) {
#pragma unroll
    for (int i = 0; i < 2; ++i) {
      int rr = lr + i * 32;
      float4 v = *(const float4*)(A + (size_t)(r0 + rr) * 224 + k0 + lk);
      As[lk + 0][rr] = v.x; As[lk + 1][rr] = v.y; As[lk + 2][rr] = v.z; As[lk + 3][rr] = v.w;
    }
#pragma unroll
    for (int i = 0; i < 4; ++i) {
      int wr = lr + i * 32;
      float4 v = *(const float4*)(W + (size_t)wr * 224 + k0 + lk);
      Ws[lk + 0][wr] = v.x; Ws[lk + 1][wr] = v.y; Ws[lk + 2][wr] = v.z; Ws[lk + 3][wr] = v.w;
    }
    __syncthreads();
#pragma unroll
    for (int kk = 0; kk < 32; ++kk) {
      float4 a = *(const float4*)&As[kk][ty * 4];
      float4 w0 = *(const float4*)&Ws[kk][tx * 8];
      float4 w1 = *(const float4*)&Ws[kk][tx * 8 + 4];
      float av[4] = {a.x, a.y, a.z, a.w};
      float wv[8] = {w0.x, w0.y, w0.z, w0.w, w1.x, w1.y, w1.z, w1.w};
#pragma unroll
      for (int i = 0; i < 4; ++i)
#pragma unroll
        for (int j = 0; j < 8; ++j) acc[i][j] = fmaf(av[i], wv[j], acc[i][j]);
    }
    __syncthreads();
  }
#pragma unroll
  for (int i = 0; i < 4; ++i) {
    int row = r0 + ty * 4 + i;
    unsigned* orow = encf2 + (size_t)row * 64;
#pragma unroll
    for (int p = 0; p < 4; ++p) {
      int col = tx * 8 + 2 * p;
      float a = fmaxf(acc[i][2 * p] + bias[col], 0.f);
      float b = fmaxf(acc[i][2 * p + 1] + bias[col + 1], 0.f);
      orow[tx * 4 + p] = h2u(pk2(a, b));
    }
  }
}

// ---------------------------------------------------------------------------
// K3: decoder input projections gi[c][v][r] (bih folded in)
// ---------------------------------------------------------------------------
__global__ __launch_bounds__(256) void k_dec_gi(
    const float* __restrict__ Wih, const float* __restrict__ bih,
    const float* __restrict__ emb, float* __restrict__ gi) {
  __shared__ float e[4][32];
  const int c = blockIdx.x, tid = threadIdx.x;
  if (tid < 128) e[tid >> 5][tid & 31] = emb[tid];
  __syncthreads();
#pragma unroll
  for (int i = 0; i < 3; ++i) {
    int r = tid + i * 256;
    const float* w = Wih + ((size_t)c * 768 + r) * 32;
    float b = bih[(size_t)c * 768 + r];
    float a0 = b, a1 = b, a2 = b, a3 = b;
#pragma unroll
    for (int k = 0; k < 32; ++k) {
      float wv = w[k];
      a0 = fmaf(wv, e[0][k], a0);
      a1 = fmaf(wv, e[1][k], a1);
      a2 = fmaf(wv, e[2][k], a2);
      a3 = fmaf(wv, e[3][k], a3);
    }
    gi[((size_t)c * 4 + 0) * 768 + r] = a0;
    gi[((size_t)c * 4 + 1) * 768 + r] = a1;
    gi[((size_t)c * 4 + 2) * 768 + r] = a2;
    gi[((size_t)c * 4 + 3) * 768 + r] = a3;
  }
}

// ---------------------------------------------------------------------------
// K3b: pack dec_Whh -> f16 chunks (v12 layout). ic = gt*16 + k*2 + hf.
// Thread (G,m,mw): row = gt*256 + 8G + (k^mw), cols 16m+8hf..+7.
// ---------------------------------------------------------------------------
__global__ __launch_bounds__(512) void k_pack_dec(
    const float* __restrict__ Whh, uint4* __restrict__ wpk) {
  const int c = blockIdx.x / 48, ic = blockIdx.x % 48;
  const int tid = threadIdx.x;
  const int G = tid >> 4, m = tid & 15, mw = m & 7;
  const int gt = ic >> 4, k = (ic & 15) >> 1, hf = ic & 1;
  const int row = gt * 256 + 8 * G + (k ^ mw);
  const float* src = Whh + ((size_t)c * 768 + row) * 256 + 16 * m + 8 * hf;
  wpk[((size_t)c * 48 + ic) * 512 + tid] =
      pack8u(*(const float4*)src, *(const float4*)(src + 4));
}

// ---------------------------------------------------------------------------
// K4: encoder GRU at 1024 threads (16 waves = 4/SIMD), fused gates, 1
// barrier/step. 64 groups x 2 units; 8 XOR slots = 2 units x 2 sources x
// 2 col-halves; ALL weights in regs (48 VGPR: 3 gates x 8 slots x uint2).
// rid = k^mw: ul=(rid>>2)&1, src=(rid>>1)&1, hf=rid&1.
// ---------------------------------------------------------------------------
#define E2LD(g, k, DST)                                                            \
  {                                                                                \
    int rid_ = (k) ^ mw;                                                           \
    int ul_ = (rid_ >> 2) & 1, hf_ = rid_ & 1;                                     \
    const float* Mx_ = ((rid_ >> 1) & 1) ? Whh : Wih;                              \
    float4 v_ = *(const float4*)(Mx_ + ((size_t)((g) * 128 + 2 * G + ul_)) * 128 + \
                                 hf_ * 64 + 4 * m);                                \
    DST.x = h2u(pk2(v_.x, v_.y));                                                  \
    DST.y = h2u(pk2(v_.z, v_.w));                                                  \
  }                                                                                \
  __builtin_amdgcn_sched_barrier(0);

__global__ __launch_bounds__(1024)
__attribute__((amdgpu_waves_per_eu(4, 4))) void k_enc_gru(
    const unsigned* __restrict__ encf2,
    const float* __restrict__ WihF, const float* __restrict__ WhhF,
    const float* __restrict__ bihF, const float* __restrict__ bhhF,
    const float* __restrict__ WihB, const float* __restrict__ WhhB,
    const float* __restrict__ bihB, const float* __restrict__ bhhB,
    float* __restrict__ dec_h0) {
  const int blk = blockIdx.x;
  const int c = blk >> 1, dir = blk & 1;
  const int tid = threadIdx.x;
  const int G = tid >> 4, m = tid & 15, mw = m & 7;

  const float* Wih = (dir ? WihB : WihF) + (size_t)c * 384 * 128;
  const float* Whh = (dir ? WhhB : WhhF) + (size_t)c * 384 * 128;
  const float* bih = (dir ? bihB : bihF) + (size_t)c * 384;
  const float* bhh = (dir ? bhhB : bhhF) + (size_t)c * 384;

  __shared__ __align__(16) unsigned x2s[2][64];
  __shared__ __align__(16) unsigned h2s[2][64];

  uint2 wr0, wr1, wr2, wr3, wr4, wr5, wr6, wr7;
  uint2 wz0, wz1, wz2, wz3, wz4, wz5, wz6, wz7;
  uint2 wn0, wn1, wn2, wn3, wn4, wn5, wn6, wn7;
  E2LD(0, 0, wr0) E2LD(0, 1, wr1) E2LD(0, 2, wr2) E2LD(0, 3, wr3)
  E2LD(0, 4, wr4) E2LD(0, 5, wr5) E2LD(0, 6, wr6) E2LD(0, 7, wr7)
  E2LD(1, 0, wz0) E2LD(1, 1, wz1) E2LD(1, 2, wz2) E2LD(1, 3, wz3)
  E2LD(1, 4, wz4) E2LD(1, 5, wz5) E2LD(1, 6, wz6) E2LD(1, 7, wz7)
  E2LD(2, 0, wn0) E2LD(2, 1, wn1) E2LD(2, 2, wn2) E2LD(2, 3, wn3)
  E2LD(2, 4, wn4) E2LD(2, 5, wn5) E2LD(2, 6, wn6) E2LD(2, 7, wn7)

  const int u = 2 * G + ((m >> 2) & 1);
  const float brz_r = bih[u] + bhh[u];
  const float brz_z = bih[128 + u] + bhh[128 + u];
  const float b_in = bih[256 + u];
  const float b_hn = bhh[256 + u];

  if (tid < 64) h2s[0][tid] = 0u;
  if (tid >= 960) {
    int lane = tid - 960;
    x2s[0][lane] = (dir == 0) ? encf2[((size_t)c * 512 + 0) * 64 + lane] : 0x3C003C00u;
  }
  float hreg = 0.f;
  __syncthreads();

  const bool s0 = (mw & 1), s1 = ((mw >> 1) & 1);

  for (int t = 0; t <= 512; ++t) {
    unsigned xpre = 0;
    if (tid >= 960 && t < 512) {
      int tn = t + 1, lane = tid - 960;
      int row = (dir == 0) ? ((tn < 512) ? tn : -1) : (512 - tn);
      xpre = (row < 0) ? 0x3C003C00u : encf2[((size_t)c * 512 + row) * 64 + lane];
    }
    uint2 xl = *(const uint2*)&x2s[t & 1][2 * m];
    uint2 xh = *(const uint2*)&x2s[t & 1][32 + 2 * m];
    uint2 hl = *(const uint2*)&h2s[t & 1][2 * m];
    uint2 hh = *(const uint2*)&h2s[t & 1][32 + 2 * m];
    // parity-preselect: slot k uses P[k&3] = act[src = (k>>1&1)^s1][hf = (k&1)^s0]
    uint2 P0 = s1 ? (s0 ? hh : hl) : (s0 ? xh : xl);
    uint2 P1 = s1 ? (s0 ? hl : hh) : (s0 ? xl : xh);
    uint2 P2 = s1 ? (s0 ? xh : xl) : (s0 ? hh : hl);
    uint2 P3 = s1 ? (s0 ? xl : xh) : (s0 ? hl : hh);
    float vR = reduce8s(d2(wr0, P0), d2(wr1, P1), d2(wr2, P2), d2(wr3, P3),
                        d2(wr4, P0), d2(wr5, P1), d2(wr6, P2), d2(wr7, P3));
    float vZ = reduce8s(d2(wz0, P0), d2(wz1, P1), d2(wz2, P2), d2(wz3, P3),
                        d2(wz4, P0), d2(wz5, P1), d2(wz6, P2), d2(wz7, P3));
    float vN = reduce8s(d2(wn0, P0), d2(wn1, P1), d2(wn2, P2), d2(wn3, P3),
                        d2(wn4, P0), d2(wn5, P1), d2(wn6, P2), d2(wn7, P3));
    // combine col-halves (rid bit0)
    float vRh = vR + __shfl_xor(vR, 1, 64);
    float vZh = vZ + __shfl_xor(vZ, 1, 64);
    float vNh = vN + __shfl_xor(vN, 1, 64);
    // combine sources (rid bit1) for r/z; exchange for n
    float vRc = vRh + __shfl_xor(vRh, 2, 64);
    float vZc = vZh + __shfl_xor(vZh, 2, 64);
    float nOth = __shfl_xor(vNh, 2, 64);
    // owner lanes (m&3)==0: rid = m&7 in {0,4} -> src=0 -> i_n self, h_n other
    float r = sigf(vRc + brz_r);
    float z = sigf(vZc + brz_z);
    float n = tanhfast(vNh + b_in + r * (nOth + b_hn));
    float hn = (1.f - z) * n + z * hreg;
    hreg = hn;
    float hnP = __shfl_xor(hn, 4, 64);  // partner unit (rid bit2)
    if (m == 0) h2s[(t + 1) & 1][G] = h2u(pk2(hn, hnP));
    if (tid >= 960 && t < 512) x2s[(t + 1) & 1][tid - 960] = xpre;
    BAR_LGKM();
  }
  if (((m & 3) == 0) && (m < 8))
    dec_h0[(size_t)c * 256 + dir * 128 + u] = hreg;
}

// ---------------------------------------------------------------------------
// K5: decoder GRU (v14 config: 12 reg / 18 LDS / 18 inline L2, 512 thr).
// ---------------------------------------------------------------------------
#define CONSX(sa, sb) dotu4(sb, g4, g5, g6, g7, dotu4(sa, g0, g1, g2, g3, 0.f))

__global__ __launch_bounds__(512) void k_dec_gru(
    const uint4* __restrict__ wpk, const float* __restrict__ bhh,
    const float* __restrict__ gi, const float* __restrict__ h0,
    const int* __restrict__ labels, unsigned* __restrict__ dhs2) {
  const int c = blockIdx.x, tid = threadIdx.x;
  const int G = tid >> 4, m = tid & 15, mw = m & 7;

  __shared__ __align__(16) unsigned h2s[2][128];
  __shared__ int labs[513];
  __shared__ __align__(16) uint4 wlds[18 * 512];  // 147456 B

  const uint4* wp = wpk + (size_t)c * 48 * 512 + tid;

  for (int j = 0; j < 18; ++j) wlds[j * 512 + tid] = wp[(12 + j) * 512];
  __builtin_amdgcn_sched_barrier(0);
  uint4 ra0 = wp[0 * 512], ra1 = wp[1 * 512], ra2 = wp[2 * 512], ra3 = wp[3 * 512];
  uint4 ra4 = wp[4 * 512], ra5 = wp[5 * 512], ra6 = wp[6 * 512], ra7 = wp[7 * 512];
  __builtin_amdgcn_sched_barrier(0);
  uint4 ra8 = wp[8 * 512], ra9 = wp[9 * 512], ra10 = wp[10 * 512], ra11 = wp[11 * 512];
  __builtin_amdgcn_sched_barrier(0);

  const int u = 8 * G + mw;
  const float bb0 = bhh[(size_t)c * 768 + u];
  const float bb1 = bhh[(size_t)c * 768 + 256 + u];
  const float bb2 = bhh[(size_t)c * 768 + 512 + u];
  const float* gib = gi + (size_t)c * 4 * 768;
  unsigned* dout = dhs2 + (size_t)c * 513 * 128 + 4 * G + (mw >> 1);

  if (tid < 512) labs[tid + 1] = labels[(size_t)c * 512 + tid];
  if (tid == 0) labs[0] = 2;  // SOS
  float hreg = h0[(size_t)c * 256 + u];
  {
    float oth = __shfl_xor(hreg, 1, 64);
    if (m < 8 && (mw & 1) == 0) h2s[0][4 * G + (mw >> 1)] = h2u(pk2(hreg, oth));
  }
  __syncthreads();

  const uint4* wl = wlds + tid;

  for (int t = 0; t <= 512; ++t) {
    uint4 sa0 = wp[30 * 512], sa1 = wp[31 * 512], sa2 = wp[32 * 512], sa3 = wp[33 * 512];
    uint4 sa4 = wp[34 * 512], sa5 = wp[35 * 512], sa6 = wp[36 * 512], sa7 = wp[37 * 512];
    uint4 ha = ((const uint4*)&h2s[t & 1][0])[2 * m];
    uint4 hb = ((const uint4*)&h2s[t & 1][0])[2 * m + 1];
    h2v g0 = u2h(ha.x), g1 = u2h(ha.y), g2 = u2h(ha.z), g3 = u2h(ha.w);
    h2v g4 = u2h(hb.x), g5 = u2h(hb.y), g6 = u2h(hb.z), g7 = u2h(hb.w);
    int sel = labs[t];
    const float* gp = gib + sel * 768;
    float giR = gp[u], giZ = gp[256 + u], giN = gp[512 + u];
    float p0 = CONSX(ra0, ra1), p1 = CONSX(ra2, ra3);
    float p2 = CONSX(ra4, ra5), p3 = CONSX(ra6, ra7);
    float p4 = CONSX(ra8, ra9), p5 = CONSX(ra10, ra11);
    float p6 = CONSX(wl[0 * 512], wl[1 * 512]);
    float p7 = CONSX(wl[2 * 512], wl[3 * 512]);
    float rsum = reduce8s(p0, p1, p2, p3, p4, p5, p6, p7);
    uint4 sb0 = wp[38 * 512], sb1 = wp[39 * 512], sb2 = wp[40 * 512], sb3 = wp[41 * 512];
    uint4 sb4 = wp[42 * 512], sb5 = wp[43 * 512], sb6 = wp[44 * 512], sb7 = wp[45 * 512];
    uint4 sb8 = wp[46 * 512], sb9 = wp[47 * 512];
    p0 = CONSX(wl[4 * 512], wl[5 * 512]);
    p1 = CONSX(wl[6 * 512], wl[7 * 512]);
    p2 = CONSX(wl[8 * 512], wl[9 * 512]);
    p3 = CONSX(wl[10 * 512], wl[11 * 512]);
    p4 = CONSX(wl[12 * 512], wl[13 * 512]);
    p5 = CONSX(wl[14 * 512], wl[15 * 512]);
    p6 = CONSX(wl[16 * 512], wl[17 * 512]);
    p7 = CONSX(sa0, sa1);
    float zsum = reduce8s(p0, p1, p2, p3, p4, p5, p6, p7);
    p0 = CONSX(sa2, sa3);
    p1 = CONSX(sa4, sa5);
    p2 = CONSX(sa6, sa7);
    p3 = CONSX(sb0, sb1);
    p4 = CONSX(sb2, sb3);
    p5 = CONSX(sb4, sb5);
    p6 = CONSX(sb6, sb7);
    p7 = CONSX(sb8, sb9);
    float nsum = reduce8s(p0, p1, p2, p3, p4, p5, p6, p7);
    float r = sigf(giR + rsum + bb0);
    float z = sigf(giZ + zsum + bb1);
    float n = tanhfast(giN + r * (nsum + bb2));
    float hn = (1.f - z) * n + z * hreg;
    hreg = hn;
    float oth = __shfl_xor(hn, 1, 64);
    if (m < 8 && (mw & 1) == 0) {
      unsigned pk = h2u(pk2(hn, oth));
      h2s[(t + 1) & 1][4 * G + (mw >> 1)] = pk;
      dout[(size_t)t * 128] = pk;
    }
    BAR_LGKM();
  }
}

// ---------------------------------------------------------------------------
// K5b: out-projection + log_softmax over 41040 rows (1 wave/row).
// ---------------------------------------------------------------------------
__global__ __launch_bounds__(256) void k_out(
    const unsigned* __restrict__ dhs2, const float* __restrict__ outW,
    const float* __restrict__ outB, float* __restrict__ out) {
  int row = blockIdx.x * 4 + (threadIdx.x >> 6);
  if (row >= 41040) return;
  int lane = threadIdx.x & 63;
  const unsigned* hp = dhs2 + (size_t)row * 128 + 2 * lane;
  h2v ha = u2h(hp[0]), hb = u2h(hp[1]);
  float h0f = (float)ha[0], h1f = (float)ha[1], h2f = (float)hb[0], h3f = (float)hb[1];
  float p0, p1, p2, p3;
  {
    const float* w0 = outW + 4 * lane;
    const float* w1 = outW + 256 + 4 * lane;
    const float* w2 = outW + 512 + 4 * lane;
    const float* w3 = outW + 768 + 4 * lane;
    p0 = h0f * w0[0] + h1f * w0[1] + h2f * w0[2] + h3f * w0[3];
    p1 = h0f * w1[0] + h1f * w1[1] + h2f * w1[2] + h3f * w1[3];
    p2 = h0f * w2[0] + h1f * w2[1] + h2f * w2[2] + h3f * w2[3];
    p3 = h0f * w3[0] + h1f * w3[1] + h2f * w3[2] + h3f * w3[3];
  }
#pragma unroll
  for (int off = 32; off > 0; off >>= 1) {
    p0 += __shfl_xor(p0, off, 64);
    p1 += __shfl_xor(p1, off, 64);
    p2 += __shfl_xor(p2, off, 64);
    p3 += __shfl_xor(p3, off, 64);
  }
  if (lane == 0) {
    float l0 = p0 + outB[0], l1 = p1 + outB[1], l2 = p2 + outB[2], l3 = p3 + outB[3];
    float mm = fmaxf(fmaxf(l0, l1), fmaxf(l2, l3));
    float s = __expf(l0 - mm) + __expf(l1 - mm) + __expf(l2 - mm) + __expf(l3 - mm);
    float lse = mm + __logf(s);
    float* o = out + (size_t)row * 4;
    o[0] = l0 - lse; o[1] = l1 - lse; o[2] = l2 - lse; o[3] = l3 - lse;
  }
}

// ---------------------------------------------------------------------------
// K6: labels (as float) and weights passthrough
// ---------------------------------------------------------------------------
__global__ void k_passthrough(const int* __restrict__ labels,
                              const float* __restrict__ weights,
                              float* __restrict__ out) {
  int i = blockIdx.x * blockDim.x + threadIdx.x;
  if (i < 40960) {
    out[164160 + i] = (float)labels[i];
    out[164160 + 40960 + i] = weights[i];
  }
}

// ---------------------------------------------------------------------------
extern "C" void kernel_launch(void* const* d_in, const int* in_sizes, int n_in,
                              void* d_out, int out_size, void* d_ws, size_t ws_size,
                              hipStream_t stream) {
  (void)in_sizes; (void)n_in; (void)out_size; (void)ws_size;
  const float* feat = (const float*)d_in[0];
  const float* score = (const float*)d_in[1];
  const float* box = (const float*)d_in[2];
  const float* orig = (const float*)d_in[3];
  const int* labels = (const int*)d_in[4];
  const float* weights = (const float*)d_in[5];
  const float* appear_W = (const float*)d_in[8];
  const float* appear_b = (const float*)d_in[9];
  const float* featlin_W = (const float*)d_in[10];
  const float* featlin_b = (const float*)d_in[11];
  const float* eWihF = (const float*)d_in[12];
  const float* eWhhF = (const float*)d_in[13];
  const float* ebihF = (const float*)d_in[14];
  const float* ebhhF = (const float*)d_in[15];
  const float* eWihB = (const float*)d_in[16];
  const float* eWhhB = (const float*)d_in[17];
  const float* ebihB = (const float*)d_in[18];
  const float* ebhhB = (const float*)d_in[19];
  const float* dec_emb = (const float*)d_in[20];
  const float* dWih = (const float*)d_in[21];
  const float* dWhh = (const float*)d_in[22];
  const float* dbih = (const float*)d_in[23];
  const float* dbhh = (const float*)d_in[24];
  const float* outW = (const float*)d_in[25];
  const float* outB = (const float*)d_in[26];
  float* out = (float*)d_out;

  char* ws = (char*)d_ws;
  float* allf = (float*)ws;                                     // 36.7MB; reused as wpack
  unsigned* encf2 = (unsigned*)(ws + (size_t)40960 * 224 * 4);  // 10.5MB
  float* dec_h0 = (float*)(ws + (size_t)40960 * 224 * 4 + (size_t)40960 * 64 * 4);
  float* dec_gi = dec_h0 + 80 * 256;                            // 80*4*768 f32
  unsigned* dhs2 = (unsigned*)(dec_gi + 80 * 4 * 768);          // 80*513*128 u32 = 21MB
  uint4* wpack = (uint4*)allf;                                  // 80*48*512*16B = 31.5MB

  k_fill_misc<<<15360, 256, 0, stream>>>(score, box, orig, allf);
  k_gemm_appear<<<640, 256, 0, stream>>>(feat, appear_W, appear_b, allf);
  k_gemm_featlin<<<640, 256, 0, stream>>>(allf, featlin_W, featlin_b, encf2);
  k_pack_dec<<<80 * 48, 512, 0, stream>>>(dWhh, wpack);
  k_dec_gi<<<80, 256, 0, stream>>>(dWih, dbih, dec_emb, dec_gi);
  k_enc_gru<<<160, 1024, 0, stream>>>(encf2, eWihF, eWhhF, ebihF, ebhhF,
                                      eWihB, eWhhB, ebihB, ebhhB, dec_h0);
  k_dec_gru<<<80, 512, 0, stream>>>(wpack, dbhh, dec_gi, dec_h0, labels, dhs2);
  k_out<<<10260, 256, 0, stream>>>(dhs2, outW, outB, out);
  k_passthrough<<<160, 256, 0, stream>>>(labels, weights, out);
}

// Round 19
// 1495.595 us; speedup vs baseline: 1.1443x; 1.1428x over previous
//
#include <hip/hip_runtime.h>

// ---------------------------------------------------------------------------
// Encoder_Decoder v19 = measured Pareto combination over rounds 11-18:
//   decoder: v14 exactly (707us best; 512thr, 12 reg / 18 LDS-resident /
//            18 inline-L2 chunks, fused gates, 1 lgkm barrier/step).
//   encoder: v15 exactly (~574us best; 512thr, waves_per_eu(2,2), all 24
//            chunks declared reg -- partially streamed by RA but fastest).
// Both GRU loops are latency-bound (step ~3300cy vs ~700cy issue floor at
// 2 waves/SIMD); 18 rounds of memory-mix and occupancy changes moved the
// decoder only within 707-942us. This is the floor configuration.
// ---------------------------------------------------------------------------

typedef __fp16 h2v __attribute__((ext_vector_type(2)));

__device__ __forceinline__ h2v pk2(float a, float b) {
  return __builtin_amdgcn_cvt_pkrtz(a, b);
}
__device__ __forceinline__ unsigned h2u(h2v h) { return __builtin_bit_cast(unsigned, h); }
__device__ __forceinline__ h2v u2h(unsigned u) { return __builtin_bit_cast(h2v, u); }
__device__ __forceinline__ float fdot2f(h2v a, h2v b, float c) {
  return __builtin_amdgcn_fdot2(a, b, c, false);
}
__device__ __forceinline__ float sigf(float x) { return 1.f / (1.f + __expf(-x)); }
__device__ __forceinline__ float tanhfast(float x) { return 2.f / (1.f + __expf(-2.f * x)) - 1.f; }

__device__ __forceinline__ uint4 pack8u(float4 a, float4 b) {
  uint4 o;
  o.x = h2u(pk2(a.x, a.y)); o.y = h2u(pk2(a.z, a.w));
  o.z = h2u(pk2(b.x, b.y)); o.w = h2u(pk2(b.z, b.w));
  return o;
}

__device__ __forceinline__ float dotu4(uint4 cv, h2v a0, h2v a1, h2v a2, h2v a3,
                                       float acc) {
  acc = fdot2f(u2h(cv.x), a0, acc);
  acc = fdot2f(u2h(cv.y), a1, acc);
  acc = fdot2f(u2h(cv.z), a2, acc);
  acc = fdot2f(u2h(cv.w), a3, acc);
  return acc;
}

template <int CTRL>
__device__ __forceinline__ float dppadd(float acc, float v) {
  int r = __builtin_amdgcn_update_dpp(0, __float_as_int(v), CTRL, 0xF, 0xF, true);
  return acc + __int_as_float(r);
}
__device__ __forceinline__ float swz4add(float acc, float v) {
  return acc + __int_as_float(__builtin_amdgcn_ds_swizzle(__float_as_int(v), 0x101F));
}

// 8 partials, slot k on lane holds row-id k^(m&7); returns row-id (m&7) sum.
__device__ __forceinline__ float reduce8s(float p0, float p1, float p2, float p3,
                                          float p4, float p5, float p6, float p7) {
  p0 = dppadd<0xB1>(p0, p1);
  p2 = dppadd<0xB1>(p2, p3);
  p4 = dppadd<0xB1>(p4, p5);
  p6 = dppadd<0xB1>(p6, p7);
  p0 = dppadd<0x4E>(p0, p2);
  p4 = dppadd<0x4E>(p4, p6);
  p0 = swz4add(p0, p4);
  p0 = dppadd<0x128>(p0, p0);
  return p0;
}

#define BAR_LGKM()                                     \
  asm volatile("s_waitcnt lgkmcnt(0)" ::: "memory");   \
  __builtin_amdgcn_s_barrier();                        \
  asm volatile("" ::: "memory");

// ---------------------------------------------------------------------------
// K0: fill allf[:,128:224]
// ---------------------------------------------------------------------------
__global__ void k_fill_misc(const float* __restrict__ score, const float* __restrict__ box,
                            const float* __restrict__ orig, float* __restrict__ allf) {
  int i = blockIdx.x * blockDim.x + threadIdx.x;
  if (i >= 40960 * 96) return;
  int row = i / 96, k = i - row * 96;
  float v;
  if (k == 0) v = score[row];
  else if (k < 5) v = box[row * 4 + (k - 1)];
  else v = orig[(size_t)row * 91 + (k - 5)];
  allf[(size_t)row * 224 + 128 + k] = v;
}

// ---------------------------------------------------------------------------
// K1: allf[:,0:128] = relu(feat @ appear_W^T + appear_b)
// ---------------------------------------------------------------------------
__global__ __launch_bounds__(256) void k_gemm_appear(
    const float* __restrict__ A, const float* __restrict__ W,
    const float* __restrict__ bias, float* __restrict__ allf) {
  __shared__ float As[32][68];
  __shared__ float Ws[32][132];
  const int tid = threadIdx.x;
  const int tx = tid & 15, ty = tid >> 4;
  const int r0 = blockIdx.x * 64;
  const int lr = tid >> 3;
  const int lk = (tid & 7) * 4;
  float acc[4][8];
#pragma unroll
  for (int i = 0; i < 4; ++i)
#pragma unroll
    for (int j = 0; j < 8; ++j) acc[i][j] = 0.f;

  for (int k0 = 0; k0 < 1024; k0 += 32) {
#pragma unroll
    for (int i = 0; i < 2; ++i) {
      int rr = lr + i * 32;
      float4 v = *(const float4*)(A + (size_t)(r0 + rr) * 1024 + k0 + lk);
      As[lk + 0][rr] = v.x; As[lk + 1][rr] = v.y; As[lk + 2][rr] = v.z; As[lk + 3][rr] = v.w;
    }
#pragma unroll
    for (int i = 0; i < 4; ++i) {
      int wr = lr + i * 32;
      float4 v = *(const float4*)(W + (size_t)wr * 1024 + k0 + lk);
      Ws[lk + 0][wr] = v.x; Ws[lk + 1][wr] = v.y; Ws[lk + 2][wr] = v.z; Ws[lk + 3][wr] = v.w;
    }
    __syncthreads();
#pragma unroll
    for (int kk = 0; kk < 32; ++kk) {
      float4 a = *(const float4*)&As[kk][ty * 4];
      float4 w0 = *(const float4*)&Ws[kk][tx * 8];
      float4 w1 = *(const float4*)&Ws[kk][tx * 8 + 4];
      float av[4] = {a.x, a.y, a.z, a.w};
      float wv[8] = {w0.x, w0.y, w0.z, w0.w, w1.x, w1.y, w1.z, w1.w};
#pragma unroll
      for (int i = 0; i < 4; ++i)
#pragma unroll
        for (int j = 0; j < 8; ++j) acc[i][j] = fmaf(av[i], wv[j], acc[i][j]);
    }
    __syncthreads();
  }
#pragma unroll
  for (int i = 0; i < 4; ++i) {
    int row = r0 + ty * 4 + i;
#pragma unroll
    for (int j = 0; j < 8; ++j) {
      int col = tx * 8 + j;
      float v = acc[i][j] + bias[col];
      allf[(size_t)row * 224 + col] = fmaxf(v, 0.f);
    }
  }
}

// ---------------------------------------------------------------------------
// K2: enc_feat = relu(allf @ featlin_W^T + b), stored packed f16x2
// ---------------------------------------------------------------------------
__global__ __launch_bounds__(256) void k_gemm_featlin(
    const float* __restrict__ A, const float* __restrict__ W,
    const float* __restrict__ bias, unsigned* __restrict__ encf2) {
  __shared__ float As[32][68];
  __shared__ float Ws[32][132];
  const int tid = threadIdx.x;
  const int tx = tid & 15, ty = tid >> 4;
  const int r0 = blockIdx.x * 64;
  const int lr = tid >> 3;
  const int lk = (tid & 7) * 4;
  float acc[4][8];
#pragma unroll
  for (int i = 0; i < 4; ++i)
#pragma unroll
    for (int j = 0; j < 8; ++j) acc[i][j] = 0.f;

  for (int k0 = 0; k0 < 224; k0 += 32) {
#pragma unroll
    for (int i = 0; i < 2; ++i) {
      int rr = lr + i * 32;
      float4 v = *(const float4*)(A + (size_t)(r0 + rr) * 224 + k0 + lk);
      As[lk + 0][rr] = v.x; As[lk + 1][rr] = v.y; As[lk + 2][rr] = v.z; As[lk + 3][rr] = v.w;
    }
#pragma unroll
    for (int i = 0; i < 4; ++i) {
      int wr = lr + i * 32;
      float4 v = *(const float4*)(W + (size_t)wr * 224 + k0 + lk);
      Ws[lk + 0][wr] = v.x; Ws[lk + 1][wr] = v.y; Ws[lk + 2][wr] = v.z; Ws[lk + 3][wr] = v.w;
    }
    __syncthreads();
#pragma unroll
    for (int kk = 0; kk < 32; ++kk) {
      float4 a = *(const float4*)&As[kk][ty * 4];
      float4 w0 = *(const float4*)&Ws[kk][tx * 8];
      float4 w1 = *(const float4*)&Ws[kk][tx * 8 + 4];
      float av[4] = {a.x, a.y, a.z, a.w};
      float wv[8] = {w0.x, w0.y, w0.z, w0.w, w1.x, w1.y, w1.z, w1.w};
#pragma unroll
      for (int i = 0; i < 4; ++i)
#pragma unroll
        for (int j = 0; j < 8; ++j) acc[i][j] = fmaf(av[i], wv[j], acc[i][j]);
    }
    __syncthreads();
  }
#pragma unroll
  for (int i = 0; i < 4; ++i) {
    int row = r0 + ty * 4 + i;
    unsigned* orow = encf2 + (size_t)row * 64;
#pragma unroll
    for (int p = 0; p < 4; ++p) {
      int col = tx * 8 + 2 * p;
      float a = fmaxf(acc[i][2 * p] + bias[col], 0.f);
      float b = fmaxf(acc[i][2 * p + 1] + bias[col + 1], 0.f);
      orow[tx * 4 + p] = h2u(pk2(a, b));
    }
  }
}

// ---------------------------------------------------------------------------
// K3: decoder input projections gi[c][v][r] (bih folded in)
// ---------------------------------------------------------------------------
__global__ __launch_bounds__(256) void k_dec_gi(
    const float* __restrict__ Wih, const float* __restrict__ bih,
    const float* __restrict__ emb, float* __restrict__ gi) {
  __shared__ float e[4][32];
  const int c = blockIdx.x, tid = threadIdx.x;
  if (tid < 128) e[tid >> 5][tid & 31] = emb[tid];
  __syncthreads();
#pragma unroll
  for (int i = 0; i < 3; ++i) {
    int r = tid + i * 256;
    const float* w = Wih + ((size_t)c * 768 + r) * 32;
    float b = bih[(size_t)c * 768 + r];
    float a0 = b, a1 = b, a2 = b, a3 = b;
#pragma unroll
    for (int k = 0; k < 32; ++k) {
      float wv = w[k];
      a0 = fmaf(wv, e[0][k], a0);
      a1 = fmaf(wv, e[1][k], a1);
      a2 = fmaf(wv, e[2][k], a2);
      a3 = fmaf(wv, e[3][k], a3);
    }
    gi[((size_t)c * 4 + 0) * 768 + r] = a0;
    gi[((size_t)c * 4 + 1) * 768 + r] = a1;
    gi[((size_t)c * 4 + 2) * 768 + r] = a2;
    gi[((size_t)c * 4 + 3) * 768 + r] = a3;
  }
}

// ---------------------------------------------------------------------------
// K3b: pack dec_Whh -> f16 chunks (v12 layout). ic = gt*16 + k*2 + hf.
// Thread (G,m,mw): row = gt*256 + 8G + (k^mw), cols 16m+8hf..+7.
// ---------------------------------------------------------------------------
__global__ __launch_bounds__(512) void k_pack_dec(
    const float* __restrict__ Whh, uint4* __restrict__ wpk) {
  const int c = blockIdx.x / 48, ic = blockIdx.x % 48;
  const int tid = threadIdx.x;
  const int G = tid >> 4, m = tid & 15, mw = m & 7;
  const int gt = ic >> 4, k = (ic & 15) >> 1, hf = ic & 1;
  const int row = gt * 256 + 8 * G + (k ^ mw);
  const float* src = Whh + ((size_t)c * 768 + row) * 256 + 16 * m + 8 * hf;
  wpk[((size_t)c * 48 + ic) * 512 + tid] =
      pack8u(*(const float4*)src, *(const float4*)(src + 4));
}

// ---------------------------------------------------------------------------
// K4: encoder GRU (v15 config): 512 threads, waves_per_eu(2,2), all 24
// weight chunks declared in registers.
// ---------------------------------------------------------------------------
#define ELOAD(gt, k, DST)                                                          \
  {                                                                                \
    int rid_ = (k) ^ mw;                                                           \
    const float* Mx_ = ((k) & 1) ? baseB : baseA;                                  \
    const float4* ps_ =                                                            \
        (const float4*)(Mx_ + ((size_t)((gt) * 128 + 4 * G + (rid_ >> 1))) * 128 + \
                        8 * m);                                                    \
    DST = pack8u(ps_[0], ps_[1]);                                                  \
  }                                                                                \
  __builtin_amdgcn_sched_barrier(0);

__global__ __launch_bounds__(512)
__attribute__((amdgpu_waves_per_eu(2, 2))) void k_enc_gru(
    const unsigned* __restrict__ encf2,
    const float* __restrict__ WihF, const float* __restrict__ WhhF,
    const float* __restrict__ bihF, const float* __restrict__ bhhF,
    const float* __restrict__ WihB, const float* __restrict__ WhhB,
    const float* __restrict__ bihB, const float* __restrict__ bhhB,
    float* __restrict__ dec_h0) {
  const int blk = blockIdx.x;
  const int c = blk >> 1, dir = blk & 1;
  const int tid = threadIdx.x;
  const int G = tid >> 4, m = tid & 15, mw = m & 7;

  const float* Wih = (dir ? WihB : WihF) + (size_t)c * 384 * 128;
  const float* Whh = (dir ? WhhB : WhhF) + (size_t)c * 384 * 128;
  const float* bih = (dir ? bihB : bihF) + (size_t)c * 384;
  const float* bhh = (dir ? bhhB : bhhF) + (size_t)c * 384;

  const float* baseA = (mw & 1) ? Whh : Wih;  // for even k
  const float* baseB = (mw & 1) ? Wih : Whh;  // for odd  k

  __shared__ __align__(16) unsigned x2s[2][64];
  __shared__ __align__(16) unsigned h2s[2][64];

  uint4 er0, er1, er2, er3, er4, er5, er6, er7;
  uint4 ez0, ez1, ez2, ez3, ez4, ez5, ez6, ez7;
  uint4 en0, en1, en2, en3, en4, en5, en6, en7;
  ELOAD(0, 0, er0) ELOAD(0, 1, er1) ELOAD(0, 2, er2) ELOAD(0, 3, er3)
  ELOAD(0, 4, er4) ELOAD(0, 5, er5) ELOAD(0, 6, er6) ELOAD(0, 7, er7)
  ELOAD(1, 0, ez0) ELOAD(1, 1, ez1) ELOAD(1, 2, ez2) ELOAD(1, 3, ez3)
  ELOAD(1, 4, ez4) ELOAD(1, 5, ez5) ELOAD(1, 6, ez6) ELOAD(1, 7, ez7)
  ELOAD(2, 0, en0) ELOAD(2, 1, en1) ELOAD(2, 2, en2) ELOAD(2, 3, en3)
  ELOAD(2, 4, en4) ELOAD(2, 5, en5) ELOAD(2, 6, en6) ELOAD(2, 7, en7)

  const int u = 4 * G + (mw >> 1);
  const float brz_r = bih[u] + bhh[u];
  const float brz_z = bih[128 + u] + bhh[128 + u];
  const float b_in = bih[256 + u];
  const float b_hn = bhh[256 + u];

  if (tid < 64) h2s[0][tid] = 0u;
  if (tid >= 448) {
    int lane = tid - 448;
    x2s[0][lane] = (dir == 0) ? encf2[((size_t)c * 512 + 0) * 64 + lane] : 0x3C003C00u;
  }
  float hreg = 0.f;
  __syncthreads();

  for (int t = 0; t <= 512; ++t) {
    unsigned xpre = 0;
    if (tid >= 448 && t < 512) {
      int tn = t + 1, lane = tid - 448;
      int row = (dir == 0) ? ((tn < 512) ? tn : -1) : (512 - tn);
      xpre = (row < 0) ? 0x3C003C00u : encf2[((size_t)c * 512 + row) * 64 + lane];
    }
    uint4 xv = ((const uint4*)&x2s[t & 1][0])[m];
    uint4 hv = ((const uint4*)&h2s[t & 1][0])[m];
    h2v x0 = u2h(xv.x), x1 = u2h(xv.y), x2 = u2h(xv.z), x3 = u2h(xv.w);
    h2v hh0 = u2h(hv.x), hh1 = u2h(hv.y), hh2 = u2h(hv.z), hh3 = u2h(hv.w);
    bool oddl = (mw & 1);
    h2v a0 = oddl ? hh0 : x0, a1 = oddl ? hh1 : x1, a2 = oddl ? hh2 : x2, a3 = oddl ? hh3 : x3;
    h2v b0 = oddl ? x0 : hh0, b1 = oddl ? x1 : hh1, b2 = oddl ? x2 : hh2, b3 = oddl ? x3 : hh3;
#define EA(ch) dotu4(ch, a0, a1, a2, a3, 0.f)
#define EB(ch) dotu4(ch, b0, b1, b2, b3, 0.f)
    float vR = reduce8s(EA(er0), EB(er1), EA(er2), EB(er3),
                        EA(er4), EB(er5), EA(er6), EB(er7));
    float vZ = reduce8s(EA(ez0), EB(ez1), EA(ez2), EB(ez3),
                        EA(ez4), EB(ez5), EA(ez6), EB(ez7));
    float vN = reduce8s(EA(en0), EB(en1), EA(en2), EB(en3),
                        EA(en4), EB(en5), EA(en6), EB(en7));
#undef EA
#undef EB
    float oR = __shfl_xor(vR, 1, 64);
    float oZ = __shfl_xor(vZ, 1, 64);
    float oN = __shfl_xor(vN, 1, 64);
    float r = sigf(vR + oR + brz_r);
    float z = sigf(vZ + oZ + brz_z);
    float i_n = oddl ? oN : vN;
    float h_n = oddl ? vN : oN;
    float n = tanhfast(i_n + b_in + r * (h_n + b_hn));
    float hn = (1.f - z) * n + z * hreg;
    hreg = hn;
    float prt = __shfl_xor(hn, 2, 64);
    if (m < 8 && (mw & 3) == 0) h2s[(t + 1) & 1][2 * G + (mw >> 2)] = h2u(pk2(hn, prt));
    if (tid >= 448 && t < 512) x2s[(t + 1) & 1][tid - 448] = xpre;
    BAR_LGKM();
  }
  if ((m < 8) && ((mw & 1) == 0))
    dec_h0[(size_t)c * 256 + dir * 128 + u] = hreg;
}

// ---------------------------------------------------------------------------
// K5: decoder GRU (v14 config: 12 reg / 18 LDS-resident / 18 inline-L2).
// 80 blocks x 512 threads, fused gates, 1 lgkm barrier/step.
// ---------------------------------------------------------------------------
#define CONSX(sa, sb) dotu4(sb, g4, g5, g6, g7, dotu4(sa, g0, g1, g2, g3, 0.f))

__global__ __launch_bounds__(512) void k_dec_gru(
    const uint4* __restrict__ wpk, const float* __restrict__ bhh,
    const float* __restrict__ gi, const float* __restrict__ h0,
    const int* __restrict__ labels, unsigned* __restrict__ dhs2) {
  const int c = blockIdx.x, tid = threadIdx.x;
  const int G = tid >> 4, m = tid & 15, mw = m & 7;

  __shared__ __align__(16) unsigned h2s[2][128];
  __shared__ int labs[513];
  __shared__ __align__(16) uint4 wlds[18 * 512];  // 147456 B

  const uint4* wp = wpk + (size_t)c * 48 * 512 + tid;

  for (int j = 0; j < 18; ++j) wlds[j * 512 + tid] = wp[(12 + j) * 512];
  __builtin_amdgcn_sched_barrier(0);
  uint4 ra0 = wp[0 * 512], ra1 = wp[1 * 512], ra2 = wp[2 * 512], ra3 = wp[3 * 512];
  uint4 ra4 = wp[4 * 512], ra5 = wp[5 * 512], ra6 = wp[6 * 512], ra7 = wp[7 * 512];
  __builtin_amdgcn_sched_barrier(0);
  uint4 ra8 = wp[8 * 512], ra9 = wp[9 * 512], ra10 = wp[10 * 512], ra11 = wp[11 * 512];
  __builtin_amdgcn_sched_barrier(0);

  const int u = 8 * G + mw;
  const float bb0 = bhh[(size_t)c * 768 + u];
  const float bb1 = bhh[(size_t)c * 768 + 256 + u];
  const float bb2 = bhh[(size_t)c * 768 + 512 + u];
  const float* gib = gi + (size_t)c * 4 * 768;
  unsigned* dout = dhs2 + (size_t)c * 513 * 128 + 4 * G + (mw >> 1);

  if (tid < 512) labs[tid + 1] = labels[(size_t)c * 512 + tid];
  if (tid == 0) labs[0] = 2;  // SOS
  float hreg = h0[(size_t)c * 256 + u];
  {
    float oth = __shfl_xor(hreg, 1, 64);
    if (m < 8 && (mw & 1) == 0) h2s[0][4 * G + (mw >> 1)] = h2u(pk2(hreg, oth));
  }
  __syncthreads();

  const uint4* wl = wlds + tid;

  for (int t = 0; t <= 512; ++t) {
    uint4 sa0 = wp[30 * 512], sa1 = wp[31 * 512], sa2 = wp[32 * 512], sa3 = wp[33 * 512];
    uint4 sa4 = wp[34 * 512], sa5 = wp[35 * 512], sa6 = wp[36 * 512], sa7 = wp[37 * 512];
    uint4 ha = ((const uint4*)&h2s[t & 1][0])[2 * m];
    uint4 hb = ((const uint4*)&h2s[t & 1][0])[2 * m + 1];
    h2v g0 = u2h(ha.x), g1 = u2h(ha.y), g2 = u2h(ha.z), g3 = u2h(ha.w);
    h2v g4 = u2h(hb.x), g5 = u2h(hb.y), g6 = u2h(hb.z), g7 = u2h(hb.w);
    int sel = labs[t];
    const float* gp = gib + sel * 768;
    float giR = gp[u], giZ = gp[256 + u], giN = gp[512 + u];
    float p0 = CONSX(ra0, ra1), p1 = CONSX(ra2, ra3);
    float p2 = CONSX(ra4, ra5), p3 = CONSX(ra6, ra7);
    float p4 = CONSX(ra8, ra9), p5 = CONSX(ra10, ra11);
    float p6 = CONSX(wl[0 * 512], wl[1 * 512]);
    float p7 = CONSX(wl[2 * 512], wl[3 * 512]);
    float rsum = reduce8s(p0, p1, p2, p3, p4, p5, p6, p7);
    uint4 sb0 = wp[38 * 512], sb1 = wp[39 * 512], sb2 = wp[40 * 512], sb3 = wp[41 * 512];
    uint4 sb4 = wp[42 * 512], sb5 = wp[43 * 512], sb6 = wp[44 * 512], sb7 = wp[45 * 512];
    uint4 sb8 = wp[46 * 512], sb9 = wp[47 * 512];
    p0 = CONSX(wl[4 * 512], wl[5 * 512]);
    p1 = CONSX(wl[6 * 512], wl[7 * 512]);
    p2 = CONSX(wl[8 * 512], wl[9 * 512]);
    p3 = CONSX(wl[10 * 512], wl[11 * 512]);
    p4 = CONSX(wl[12 * 512], wl[13 * 512]);
    p5 = CONSX(wl[14 * 512], wl[15 * 512]);
    p6 = CONSX(wl[16 * 512], wl[17 * 512]);
    p7 = CONSX(sa0, sa1);
    float zsum = reduce8s(p0, p1, p2, p3, p4, p5, p6, p7);
    p0 = CONSX(sa2, sa3);
    p1 = CONSX(sa4, sa5);
    p2 = CONSX(sa6, sa7);
    p3 = CONSX(sb0, sb1);
    p4 = CONSX(sb2, sb3);
    p5 = CONSX(sb4, sb5);
    p6 = CONSX(sb6, sb7);
    p7 = CONSX(sb8, sb9);
    float nsum = reduce8s(p0, p1, p2, p3, p4, p5, p6, p7);
    float r = sigf(giR + rsum + bb0);
    float z = sigf(giZ + zsum + bb1);
    float n = tanhfast(giN + r * (nsum + bb2));
    float hn = (1.f - z) * n + z * hreg;
    hreg = hn;
    float oth = __shfl_xor(hn, 1, 64);
    if (m < 8 && (mw & 1) == 0) {
      unsigned pk = h2u(pk2(hn, oth));
      h2s[(t + 1) & 1][4 * G + (mw >> 1)] = pk;
      dout[(size_t)t * 128] = pk;
    }
    BAR_LGKM();
  }
}

// ---------------------------------------------------------------------------
// K5b: out-projection + log_softmax over 41040 rows (1 wave/row).
// ---------------------------------------------------------------------------
__global__ __launch_bounds__(256) void k_out(
    const unsigned* __restrict__ dhs2, const float* __restrict__ outW,
    const float* __restrict__ outB, float* __restrict__ out) {
  int row = blockIdx.x * 4 + (threadIdx.x >> 6);
  if (row >= 41040) return;
  int lane = threadIdx.x & 63;
  const unsigned* hp = dhs2 + (size_t)row * 128 + 2 * lane;
  h2v ha = u2h(hp[0]), hb = u2h(hp[1]);
  float h0f = (float)ha[0], h1f = (float)ha[1], h2f = (float)hb[0], h3f = (float)hb[1];
  float p0, p1, p2, p3;
  {
    const float* w0 = outW + 4 * lane;
    const float* w1 = outW + 256 + 4 * lane;
    const float* w2 = outW + 512 + 4 * lane;
    const float* w3 = outW + 768 + 4 * lane;
    p0 = h0f * w0[0] + h1f * w0[1] + h2f * w0[2] + h3f * w0[3];
    p1 = h0f * w1[0] + h1f * w1[1] + h2f * w1[2] + h3f * w1[3];
    p2 = h0f * w2[0] + h1f * w2[1] + h2f * w2[2] + h3f * w2[3];
    p3 = h0f * w3[0] + h1f * w3[1] + h2f * w3[2] + h3f * w3[3];
  }
#pragma unroll
  for (int off = 32; off > 0; off >>= 1) {
    p0 += __shfl_xor(p0, off, 64);
    p1 += __shfl_xor(p1, off, 64);
    p2 += __shfl_xor(p2, off, 64);
    p3 += __shfl_xor(p3, off, 64);
  }
  if (lane == 0) {
    float l0 = p0 + outB[0], l1 = p1 + outB[1], l2 = p2 + outB[2], l3 = p3 + outB[3];
    float mm = fmaxf(fmaxf(l0, l1), fmaxf(l2, l3));
    float s = __expf(l0 - mm) + __expf(l1 - mm) + __expf(l2 - mm) + __expf(l3 - mm);
    float lse = mm + __logf(s);
    float* o = out + (size_t)row * 4;
    o[0] = l0 - lse; o[1] = l1 - lse; o[2] = l2 - lse; o[3] = l3 - lse;
  }
}

// ---------------------------------------------------------------------------
// K6: labels (as float) and weights passthrough
// ---------------------------------------------------------------------------
__global__ void k_passthrough(const int* __restrict__ labels,
                              const float* __restrict__ weights,
                              float* __restrict__ out) {
  int i = blockIdx.x * blockDim.x + threadIdx.x;
  if (i < 40960) {
    out[164160 + i] = (float)labels[i];
    out[164160 + 40960 + i] = weights[i];
  }
}

// ---------------------------------------------------------------------------
extern "C" void kernel_launch(void* const* d_in, const int* in_sizes, int n_in,
                              void* d_out, int out_size, void* d_ws, size_t ws_size,
                              hipStream_t stream) {
  (void)in_sizes; (void)n_in; (void)out_size; (void)ws_size;
  const float* feat = (const float*)d_in[0];
  const float* score = (const float*)d_in[1];
  const float* box = (const float*)d_in[2];
  const float* orig = (const float*)d_in[3];
  const int* labels = (const int*)d_in[4];
  const float* weights = (const float*)d_in[5];
  const float* appear_W = (const float*)d_in[8];
  const float* appear_b = (const float*)d_in[9];
  const float* featlin_W = (const float*)d_in[10];
  const float* featlin_b = (const float*)d_in[11];
  const float* eWihF = (const float*)d_in[12];
  const float* eWhhF = (const float*)d_in[13];
  const float* ebihF = (const float*)d_in[14];
  const float* ebhhF = (const float*)d_in[15];
  const float* eWihB = (const float*)d_in[16];
  const float* eWhhB = (const float*)d_in[17];
  const float* ebihB = (const float*)d_in[18];
  const float* ebhhB = (const float*)d_in[19];
  const float* dec_emb = (const float*)d_in[20];
  const float* dWih = (const float*)d_in[21];
  const float* dWhh = (const float*)d_in[22];
  const float* dbih = (const float*)d_in[23];
  const float* dbhh = (const float*)d_in[24];
  const float* outW = (const float*)d_in[25];
  const float* outB = (const float*)d_in[26];
  float* out = (float*)d_out;

  char* ws = (char*)d_ws;
  float* allf = (float*)ws;                                     // 36.7MB; reused as wpack
  unsigned* encf2 = (unsigned*)(ws + (size_t)40960 * 224 * 4);  // 10.5MB
  float* dec_h0 = (float*)(ws + (size_t)40960 * 224 * 4 + (size_t)40960 * 64 * 4);
  float* dec_gi = dec_h0 + 80 * 256;                            // 80*4*768 f32
  unsigned* dhs2 = (unsigned*)(dec_gi + 80 * 4 * 768);          // 80*513*128 u32 = 21MB
  uint4* wpack = (uint4*)allf;                                  // 80*48*512*16B = 31.5MB

  k_fill_misc<<<15360, 256, 0, stream>>>(score, box, orig, allf);
  k_gemm_appear<<<640, 256, 0, stream>>>(feat, appear_W, appear_b, allf);
  k_gemm_featlin<<<640, 256, 0, stream>>>(allf, featlin_W, featlin_b, encf2);
  k_pack_dec<<<80 * 48, 512, 0, stream>>>(dWhh, wpack);
  k_dec_gi<<<80, 256, 0, stream>>>(dWih, dbih, dec_emb, dec_gi);
  k_enc_gru<<<160, 512, 0, stream>>>(encf2, eWihF, eWhhF, ebihF, ebhhF,
                                     eWihB, eWhhB, ebihB, ebhhB, dec_h0);
  k_dec_gru<<<80, 512, 0, stream>>>(wpack, dbhh, dec_gi, dec_h0, labels, dhs2);
  k_out<<<10260, 256, 0, stream>>>(dhs2, outW, outB, out);
  k_passthrough<<<160, 256, 0, stream>>>(labels, weights, out);
}